// Round 2
// baseline (70.971 us; speedup 1.0000x reference)
//
#include <hip/hip_runtime.h>
#include <hip/hip_bf16.h>

typedef __attribute__((ext_vector_type(8))) short bf16x8;
typedef __attribute__((ext_vector_type(4))) float f32x4;

#define D_K    256
#define WH     784
#define WHH    392
#define P_REAL 511
#define P_PAD  512
#define C_OUT  200
#define NLEAF  512
#define TDEPTH 9

#define NT      32
#define NTILES  13          // 12*32 + 8 tail (clamped duplicate columns)
#define XS_STRIDE 288       // ushorts per LDS n-row

// workspace offsets (bytes)
#define WS_PROTO 0
#define WS_P2    (P_PAD*D_K*2)            // 262144
#define WS_PM    (WS_P2 + P_PAD*4)        // 264192  pm[128][2][512] f32
#define WS_DS    (WS_PM + 128*2*P_PAD*4)  // 788480
// total: 788480 + 512*200*4 = 1198080 bytes

static __device__ __forceinline__ unsigned short f2bf(float x) {
    union { float f; unsigned int u; } v; v.f = x;
    unsigned int r = v.u + 0x7FFFu + ((v.u >> 16) & 1u);   // RNE
    return (unsigned short)(r >> 16);
}

// swizzled LDS index (ushort units): XOR row bits into byte bits 4..6;
// bijective per row, keeps 8B-write / 16B-read alignment
static __device__ __forceinline__ int xs_idx(int n, int k) {
    return (n * XS_STRIDE + k) ^ ((n & 0x1C) << 1);
}

// --- fused prep (proto -> bf16(-2p) + p2) and softmax(leaf_params) --------
__global__ __launch_bounds__(64)
void prep2_kernel(const float* __restrict__ protos, const float* __restrict__ lp,
                  unsigned short* __restrict__ pb, float* __restrict__ p2,
                  float* __restrict__ ds) {
    int bid = blockIdx.x;
    int l = threadIdx.x;
    if (bid < P_PAD) {
        int p = bid;
        f32x4 v = {0.f, 0.f, 0.f, 0.f};
        if (p < P_REAL)
            v = *reinterpret_cast<const f32x4*>(protos + (size_t)p * D_K + 4 * l);
        ushort4 w;
        w.x = f2bf(-2.f * v[0]); w.y = f2bf(-2.f * v[1]);
        w.z = f2bf(-2.f * v[2]); w.w = f2bf(-2.f * v[3]);
        *reinterpret_cast<ushort4*>(pb + (size_t)p * D_K + 4 * l) = w;
        float s = v[0]*v[0] + v[1]*v[1] + v[2]*v[2] + v[3]*v[3];
#pragma unroll
        for (int m = 32; m >= 1; m >>= 1) s += __shfl_xor(s, m, 64);
        if (l == 0) p2[p] = s;
    } else {
        int row = bid - P_PAD;
        float v[4];
        float mx = -3.4e38f;
#pragma unroll
        for (int i = 0; i < 4; ++i) {
            int c = l + 64 * i;
            v[i] = (c < C_OUT) ? lp[(size_t)row * C_OUT + c] : -3.4e38f;
            mx = fmaxf(mx, v[i]);
        }
#pragma unroll
        for (int m = 32; m >= 1; m >>= 1) mx = fmaxf(mx, __shfl_xor(mx, m, 64));
        float sum = 0.f;
#pragma unroll
        for (int i = 0; i < 4; ++i) {
            int c = l + 64 * i;
            if (c < C_OUT) { v[i] = expf(v[i] - mx); sum += v[i]; }
        }
#pragma unroll
        for (int m = 32; m >= 1; m >>= 1) sum += __shfl_xor(sum, m, 64);
        float inv = 1.f / sum;
#pragma unroll
        for (int i = 0; i < 4; ++i) {
            int c = l + 64 * i;
            if (c < C_OUT) ds[(size_t)row * C_OUT + c] = v[i] * inv;
        }
    }
}

// --- main: pm[b][whh][p] = min over this wh-half of (x2 - 2xp) ------------
// grid 512 = ph*256 + (b*2 + whh); 4 waves, 64 p-rows/wave
__global__ __launch_bounds__(256, 2)
void proto_min_kernel(const float* __restrict__ xs,
                      const unsigned short* __restrict__ pb,
                      float* __restrict__ pm) {
    __shared__ unsigned short Xs[NT * XS_STRIDE];   // 18432 B
    __shared__ float x2buf[8][4][4];                // [n4][c][wv]

    const int tid  = threadIdx.x;
    const int wv   = tid >> 6;
    const int lane = tid & 63;
    const int g    = lane >> 4;   // 0..3
    const int lr   = lane & 15;   // 0..15

    const int ph  = blockIdx.x >> 8;   // p-half; pairs (i, i+256) share xs region
    const int j   = blockIdx.x & 255;
    const int b   = j >> 1;
    const int whh = j & 1;
    const int p0  = ph * 256;

    const float* xb = xs + (size_t)b * (D_K * WH) + whh * WHH;

    // A fragments: -2*proto bf16, 64 rows x full K per wave, in registers
    bf16x8 af[4][8];
#pragma unroll
    for (int mf = 0; mf < 4; ++mf) {
        const unsigned short* rp = pb + (size_t)(p0 + 64*wv + 16*mf + lr) * D_K + 8*g;
#pragma unroll
        for (int ks = 0; ks < 8; ++ks)
            af[mf][ks] = *reinterpret_cast<const bf16x8*>(rp + 32*ks);
    }

    const int n4  = tid & 7;    // col-quad within 32-col tile
    const int kq0 = tid >> 3;   // 0..31; k-quads kq0 and kq0+32

    float rmin[4][4];
#pragma unroll
    for (int mf = 0; mf < 4; ++mf)
#pragma unroll
        for (int r = 0; r < 4; ++r) rmin[mf][r] = 3.0e38f;

    // prefetch tile 0
    f32x4 ld[2][4];
    {
        int colb = 4 * n4;
#pragma unroll
        for (int i = 0; i < 2; ++i) {
            const float* rowp = xb + (size_t)(4*(kq0 + 32*i)) * WH + colb;
#pragma unroll
            for (int r = 0; r < 4; ++r)
                ld[i][r] = *reinterpret_cast<const f32x4*>(rowp + r * WH);
        }
    }

    for (int t = 0; t < NTILES; ++t) {
        // ---- convert + 4x4 transpose write + x2 partials
        f32x4 x2q = {0.f, 0.f, 0.f, 0.f};
#pragma unroll
        for (int i = 0; i < 2; ++i) {
            int kq = kq0 + 32*i;
#pragma unroll
            for (int r = 0; r < 4; ++r) {
                f32x4 v = ld[i][r];
                x2q[0] += v[0]*v[0]; x2q[1] += v[1]*v[1];
                x2q[2] += v[2]*v[2]; x2q[3] += v[3]*v[3];
            }
#pragma unroll
            for (int c = 0; c < 4; ++c) {
                ushort4 w;
                w.x = f2bf(ld[i][0][c]);
                w.y = f2bf(ld[i][1][c]);
                w.z = f2bf(ld[i][2][c]);
                w.w = f2bf(ld[i][3][c]);
                *reinterpret_cast<ushort4*>(&Xs[xs_idx(4*n4 + c, 4*kq)]) = w;
            }
        }
        // wave-partial x2 per column quad (lanes sharing n4: masks 8,16,32)
#pragma unroll
        for (int c = 0; c < 4; ++c) {
            x2q[c] += __shfl_xor(x2q[c], 8, 64);
            x2q[c] += __shfl_xor(x2q[c], 16, 64);
            x2q[c] += __shfl_xor(x2q[c], 32, 64);
        }
        if (lane < 8) {
#pragma unroll
            for (int c = 0; c < 4; ++c) x2buf[lane][c][wv] = x2q[c];
        }

        __syncthreads();

        // ---- T14: issue next tile's global loads before the MFMA phase
        if (t + 1 < NTILES) {
            int colb = (t + 1) * NT + 4 * n4;
            if (colb > WHH - 4) colb = WHH - 4;   // tail: duplicate columns
#pragma unroll
            for (int i = 0; i < 2; ++i) {
                const float* rowp = xb + (size_t)(4*(kq0 + 32*i)) * WH + colb;
#pragma unroll
                for (int r = 0; r < 4; ++r)
                    ld[i][r] = *reinterpret_cast<const f32x4*>(rowp + r * WH);
            }
        }

        // ---- full x2 for this lane's 2 columns (one b128 + 3 adds each)
        float x2v[2];
#pragma unroll
        for (int nf = 0; nf < 2; ++nf) {
            int nn = 16*nf + lr;
            f32x4 q = *reinterpret_cast<const f32x4*>(&x2buf[nn >> 2][nn & 3][0]);
            x2v[nf] = (q[0] + q[1]) + (q[2] + q[3]);
        }

        // ---- GEMM with C initialized to x2 (C col = lane&15, same per reg)
        f32x4 acc[4][2];
#pragma unroll
        for (int mf = 0; mf < 4; ++mf)
#pragma unroll
            for (int nf = 0; nf < 2; ++nf)
                acc[mf][nf] = (f32x4){x2v[nf], x2v[nf], x2v[nf], x2v[nf]};

#pragma unroll
        for (int ks = 0; ks < 8; ++ks) {
            bf16x8 bfr[2];
#pragma unroll
            for (int nf = 0; nf < 2; ++nf)
                bfr[nf] = *reinterpret_cast<const bf16x8*>(&Xs[xs_idx(16*nf + lr, 32*ks + 8*g)]);
#pragma unroll
            for (int mf = 0; mf < 4; ++mf)
#pragma unroll
                for (int nf = 0; nf < 2; ++nf)
                    acc[mf][nf] = __builtin_amdgcn_mfma_f32_16x16x32_bf16(
                        af[mf][ks], bfr[nf], acc[mf][nf], 0, 0, 0);
        }

        // ---- running min over this tile's columns
#pragma unroll
        for (int nf = 0; nf < 2; ++nf)
#pragma unroll
            for (int mf = 0; mf < 4; ++mf)
#pragma unroll
                for (int r = 0; r < 4; ++r)
                    rmin[mf][r] = fminf(rmin[mf][r], acc[mf][nf][r]);

        __syncthreads();
    }

    // min across the 16 column-lanes (flips only lr bits; g preserved)
#pragma unroll
    for (int mf = 0; mf < 4; ++mf)
#pragma unroll
        for (int r = 0; r < 4; ++r) {
            float v = rmin[mf][r];
#pragma unroll
            for (int m = 1; m <= 8; m <<= 1)
                v = fminf(v, __shfl_xor(v, m, 64));
            rmin[mf][r] = v;
        }

    if (lr == 0) {
        float* pmw = pm + ((size_t)b * 2 + whh) * P_PAD;
#pragma unroll
        for (int mf = 0; mf < 4; ++mf)
#pragma unroll
            for (int r = 0; r < 4; ++r)
                pmw[p0 + 64*wv + 16*mf + 4*g + r] = rmin[mf][r];
    }
}

// --- combine halves + exp(-sqrt) + tree path products + pa @ ds -----------
__global__ __launch_bounds__(256)
void out_kernel(const float* __restrict__ pm, const float* __restrict__ p2,
                const float* __restrict__ ds, float* __restrict__ out) {
    __shared__ float sim[NLEAF];
    __shared__ float pa[NLEAF];
    int b = blockIdx.x;
    int t = threadIdx.x;
    const float* pm0 = pm + (size_t)b * 2 * P_PAD;
#pragma unroll
    for (int j = 0; j < 2; ++j) {
        int p = t + 256 * j;
        float m = fminf(pm0[p], pm0[P_PAD + p]);
        float sq = m + p2[p];
        sim[p] = expf(-sqrtf(fabsf(sq) + 1e-14f));
    }
    __syncthreads();
#pragma unroll
    for (int j = 0; j < 2; ++j) {
        int leaf = t + 256 * j;
        int node = 0;
        float prod = 1.f;
#pragma unroll
        for (int st = 0; st < TDEPTH; ++st) {
            int bit = (leaf >> (TDEPTH - 1 - st)) & 1;
            float sv = sim[node];
            prod *= bit ? sv : (1.f - sv);
            node = 2 * node + 1 + bit;
        }
        pa[leaf] = prod;
    }
    __syncthreads();
    if (t < C_OUT) {
        float a0 = 0.f, a1 = 0.f, a2 = 0.f, a3 = 0.f;
        for (int l = 0; l < NLEAF; l += 4) {
            a0 += pa[l + 0] * ds[(size_t)(l + 0) * C_OUT + t];
            a1 += pa[l + 1] * ds[(size_t)(l + 1) * C_OUT + t];
            a2 += pa[l + 2] * ds[(size_t)(l + 2) * C_OUT + t];
            a3 += pa[l + 3] * ds[(size_t)(l + 3) * C_OUT + t];
        }
        out[(size_t)b * C_OUT + t] = (a0 + a1) + (a2 + a3);
    }
}

extern "C" void kernel_launch(void* const* d_in, const int* in_sizes, int n_in,
                              void* d_out, int out_size, void* d_ws, size_t ws_size,
                              hipStream_t stream) {
    (void)in_sizes; (void)n_in; (void)out_size; (void)ws_size;
    const float* xs     = (const float*)d_in[0];
    const float* protos = (const float*)d_in[1];
    const float* lp     = (const float*)d_in[2];
    float* out = (float*)d_out;

    char* ws = (char*)d_ws;
    unsigned short* pb = (unsigned short*)(ws + WS_PROTO);
    float* p2   = (float*)(ws + WS_P2);
    float* pm   = (float*)(ws + WS_PM);
    float* dsm  = (float*)(ws + WS_DS);

    prep2_kernel<<<1024, 64, 0, stream>>>(protos, lp, pb, p2, dsm);
    proto_min_kernel<<<512, 256, 0, stream>>>(xs, pb, pm);
    out_kernel<<<128, 256, 0, stream>>>(pm, p2, dsm, out);
}